// Round 3
// baseline (393.751 us; speedup 1.0000x reference)
//
#include <hip/hip_runtime.h>

// ---------------------------------------------------------------------------
// BEiT-style attention block on MI355X (gfx950), bf16-MFMA pipeline.
// B=64, N=257 (pad 272), DIM=1024, HEADS=16, d=64.
// Round 3: both GEMMs moved to the 256x256 8-phase schedule (T2+T3+T4+T5):
// 8 waves, BK=64, kk-slab LDS layout, lag-1 half-tile staging, counted
// vmcnt(6) once per K-tile, raw s_barrier, setprio around MFMA clusters.
// ---------------------------------------------------------------------------

typedef __attribute__((ext_vector_type(8))) short bf16x8;
typedef __attribute__((ext_vector_type(4))) float f32x4;

#define MFMA16(A, B, C) __builtin_amdgcn_mfma_f32_16x16x32_bf16((A), (B), (C), 0, 0, 0)

#define MV   16448   // valid rows = B*N
#define KDIM 1024
#define SEQ  257
#define SEQP 272
#define VCOLS 320
#define AROWMAX 16511  // xb has 16512 allocated rows; clamp staging reads

__device__ __forceinline__ void gll16(void* lds, const void* g) {
    __builtin_amdgcn_global_load_lds(
        (const __attribute__((address_space(1))) void*)g,
        (__attribute__((address_space(3))) void*)lds,
        16, 0, 0);
}

__device__ __forceinline__ unsigned short f2bf(float f) {
    union { float f; unsigned int u; } x;
    x.f = f;
    unsigned int r = x.u + 0x7FFFu + ((x.u >> 16) & 1u);  // RNE
    return (unsigned short)(r >> 16);
}

// ---------------------------------------------------------------------------
__global__ __launch_bounds__(256) void convert_k(
    const float* __restrict__ x, const float* __restrict__ wq, const float* __restrict__ wp,
    unsigned short* __restrict__ xb, unsigned short* __restrict__ wqb, unsigned short* __restrict__ wpb)
{
    const int XT = MV * KDIM / 4;
    const int QT = 3072 * KDIM / 4;
    const int PT = KDIM * KDIM / 4;
    const int total = XT + QT + PT;
    for (int i = blockIdx.x * blockDim.x + threadIdx.x; i < total; i += gridDim.x * blockDim.x) {
        const float4* s; unsigned short* d; int g;
        if (i < XT)            { s = (const float4*)x;  d = xb;  g = i; }
        else if (i < XT + QT)  { s = (const float4*)wq; d = wqb; g = i - XT; }
        else                   { s = (const float4*)wp; d = wpb; g = i - XT - QT; }
        float4 v = s[g];
        ushort4 u;
        u.x = f2bf(v.x); u.y = f2bf(v.y); u.z = f2bf(v.z); u.w = f2bf(v.w);
        *(ushort4*)(d + (size_t)g * 4) = u;
    }
}

// ---------------------------------------------------------------------------
__global__ __launch_bounds__(256) void bias_k(
    const float* __restrict__ table, const int* __restrict__ rpi, float* __restrict__ biasb)
{
    const int total = 16 * SEQP * SEQP;
    for (int i = blockIdx.x * blockDim.x + threadIdx.x; i < total; i += gridDim.x * blockDim.x) {
        int h = i / (SEQP * SEQP);
        int rem = i - h * (SEQP * SEQP);
        int q = rem / SEQP;
        int k = rem - q * SEQP;
        float v = 0.f;
        if (q < SEQ && k < SEQ) v = table[rpi[q * SEQ + k] * 16 + h];
        biasb[i] = v;
    }
}

// ---------------------------------------------------------------------------
// 256x256 8-phase GEMM: C[m][n] = sum_k A[m][k]*W[n][k], A/W row-major bf16,
// K = 1024 (16 K-tiles of 64). 512 threads = 8 waves (2Mx4N).
// LDS per buffer: A slabs [kk][16 subtiles][16x32], B same; dbuf = 128 KiB.
// Per tile u (buffer p=u&1), phases (kk-half, m-half):
//   ph1 (kk0,mh0): read A-kk0-mh0 + B-kk0;  stage A1(u+1) -> buf p^1
//   ph2 (kk0,mh1): read A-kk0-mh1 (B reuse); stage B0(u+2) -> buf p
//   ph3 (kk1,mh0): read A-kk1-mh0 + B-kk1;  stage A0(u+2) -> buf p
//   ph4 (kk1,mh1): read A-kk1-mh1 (B reuse); stage B1(u+2) -> buf p
//   each phase: [ds_reads][stage][bar][lgkm0][prio1][16 MFMA][prio0][bar]
//   vmcnt(6) before ph4's trailing barrier (tile boundary); vmcnt(0) at u=14.
// Retirement proof: region staged in phase q was last read in phase q-1,
// whose reads completed (lgkm0) before its MFMA and trailing barrier.
// ---------------------------------------------------------------------------
template <int NTN, int EPI>
__global__ __launch_bounds__(512, 2) void gemm8(
    const unsigned short* __restrict__ A,
    const unsigned short* __restrict__ W,
    const float* __restrict__ f0,      // q_bias | proj_b
    const float* __restrict__ f1,      // v_bias | unused
    unsigned short* __restrict__ o0,   // q [bh][272][64]
    unsigned short* __restrict__ o1,   // k [bh][272][64]
    unsigned short* __restrict__ o2,   // v^T [bh][64][320]
    float* __restrict__ fout)          // proj out [MV][1024]
{
    __shared__ __attribute__((aligned(16))) unsigned short smem[65536];  // 128 KiB
    char* smemb = (char*)smem;

    const int tid = threadIdx.x;
    const int lane = tid & 63;
    const int wid = tid >> 6;
    const int wr = wid >> 2;        // 0..1
    const int wc = wid & 3;         // 0..3

    // XCD-aware bijective block swizzle (m204)
    const int nwg = gridDim.x;
    const int orig = blockIdx.x;
    const int q8 = nwg >> 3, r8 = nwg & 7;
    const int xcd = orig & 7, loc = orig >> 3;
    const int wg = (xcd < r8 ? xcd * (q8 + 1) : r8 * (q8 + 1) + (xcd - r8) * q8) + loc;
    const int mt = wg / NTN;
    const int m0 = mt * 256;
    const int n0 = (wg - mt * NTN) * 256;

    // ---- staging constants (per thread) ----
    const int r4 = lane >> 2;                       // subtile row 0..15
    const int cb = (lane & 3) << 4;                 // byte col 0/16/32/48
    const int csw = cb ^ (((r4 >> 1) & 3) << 4);    // swizzled source col
    const int c0 = wid * 2, c1 = c0 + 1;            // this wave's subtiles
    int ar0 = m0 + c0 * 16 + r4; if (ar0 > AROWMAX) ar0 = AROWMAX;
    int ar1 = m0 + c1 * 16 + r4; if (ar1 > AROWMAX) ar1 = AROWMAX;
    const unsigned short* aS0 = A + (size_t)ar0 * KDIM + (csw >> 1);
    const unsigned short* aS1 = A + (size_t)ar1 * KDIM + (csw >> 1);
    const unsigned short* bS0 = W + (size_t)(n0 + c0 * 16 + r4) * KDIM + (csw >> 1);
    const unsigned short* bS1 = W + (size_t)(n0 + c1 * 16 + r4) * KDIM + (csw >> 1);

    // ---- fragment-read constant: row=lane&15, chunk=(lane>>4)^swz(row) ----
    const int aoff = (lane & 15) * 64 + ((((lane >> 4) ^ ((lane >> 1) & 3)) & 3) << 4);

#define STAGE_A(PAR, KK, GK) do { \
    gll16(smemb + (PAR) * 65536 + (KK) * 16384 + c0 * 1024, aS0 + (GK)); \
    gll16(smemb + (PAR) * 65536 + (KK) * 16384 + c1 * 1024, aS1 + (GK)); } while (0)
#define STAGE_B(PAR, KK, GK) do { \
    gll16(smemb + 32768 + (PAR) * 65536 + (KK) * 16384 + c0 * 1024, bS0 + (GK)); \
    gll16(smemb + 32768 + (PAR) * 65536 + (KK) * 16384 + c1 * 1024, bS1 + (GK)); } while (0)
#define BAR() do { asm volatile("" ::: "memory"); __builtin_amdgcn_s_barrier(); \
                   asm volatile("" ::: "memory"); } while (0)
#define WLG() asm volatile("s_waitcnt lgkmcnt(0)" ::: "memory")
#define LDA4(PAR, KK, MH) do { _Pragma("unroll") for (int mi2 = 0; mi2 < 4; ++mi2) \
    afr[mi2] = *(const bf16x8*)(smemb + (PAR) * 65536 + (KK) * 16384 + \
                                ((wr * 8 + (MH) * 4 + mi2) << 10) + aoff); } while (0)
#define LDB4(PAR, KK) do { _Pragma("unroll") for (int ni = 0; ni < 4; ++ni) \
    bfr[ni] = *(const bf16x8*)(smemb + 32768 + (PAR) * 65536 + (KK) * 16384 + \
                               ((wc * 4 + ni) << 10) + aoff); } while (0)
#define MFMA_PH(MH) do { _Pragma("unroll") for (int mi2 = 0; mi2 < 4; ++mi2) \
    _Pragma("unroll") for (int ni = 0; ni < 4; ++ni) \
      acc[(MH) * 4 + mi2][ni] = MFMA16(afr[mi2], bfr[ni], acc[(MH) * 4 + mi2][ni]); } while (0)

    f32x4 acc[8][4];
#pragma unroll
    for (int i = 0; i < 8; ++i)
#pragma unroll
        for (int j = 0; j < 4; ++j) acc[i][j] = 0.f;

    bf16x8 afr[4], bfr[4];

    // ---- prologue: tile0 (4 half-tiles) + tile1 (first 3 half-tiles) ----
    STAGE_B(0, 0, 0);
    STAGE_A(0, 0, 0);
    STAGE_B(0, 1, 32);
    STAGE_A(0, 1, 32);
    STAGE_B(1, 0, 64);
    STAGE_A(1, 0, 64);
    STAGE_B(1, 1, 96);
    asm volatile("s_waitcnt vmcnt(6)" ::: "memory");   // tile0 landed
    BAR();

#define TILE(U, PAR) do { \
    /* PH1: kk0 mh0 */ \
    LDA4(PAR, 0, 0); LDB4(PAR, 0); \
    if ((U) + 1 < 16) STAGE_A(1 - (PAR), 1, ((U) + 1) * 64 + 32); \
    BAR(); WLG(); __builtin_amdgcn_s_setprio(1); MFMA_PH(0); __builtin_amdgcn_s_setprio(0); BAR(); \
    /* PH2: kk0 mh1 */ \
    LDA4(PAR, 0, 1); \
    if ((U) + 2 < 16) STAGE_B(PAR, 0, ((U) + 2) * 64); \
    BAR(); WLG(); __builtin_amdgcn_s_setprio(1); MFMA_PH(1); __builtin_amdgcn_s_setprio(0); BAR(); \
    /* PH3: kk1 mh0 */ \
    LDA4(PAR, 1, 0); LDB4(PAR, 1); \
    if ((U) + 2 < 16) STAGE_A(PAR, 0, ((U) + 2) * 64); \
    BAR(); WLG(); __builtin_amdgcn_s_setprio(1); MFMA_PH(0); __builtin_amdgcn_s_setprio(0); BAR(); \
    /* PH4: kk1 mh1 */ \
    LDA4(PAR, 1, 1); \
    if ((U) + 2 < 16) STAGE_B(PAR, 1, ((U) + 2) * 64 + 32); \
    BAR(); WLG(); __builtin_amdgcn_s_setprio(1); MFMA_PH(1); __builtin_amdgcn_s_setprio(0); \
    if ((U) < 14)       { asm volatile("s_waitcnt vmcnt(6)" ::: "memory"); } \
    else if ((U) == 14) { asm volatile("s_waitcnt vmcnt(0)" ::: "memory"); } \
    BAR(); \
} while (0)

#pragma unroll 1
    for (int up = 0; up < 8; ++up) {
        const int u0 = up * 2;
        TILE(u0, 0);
        TILE(u0 + 1, 1);
    }

    // ---- epilogue: C/D layout col=lane&15 (n), row=(lane>>4)*4+j (m) ----
    if (EPI == 0) {
        const int which = n0 >> 10;  // 0=q 1=k 2=v (uniform per block)
#pragma unroll
        for (int ni = 0; ni < 4; ++ni) {
            const int n = n0 + wc * 64 + ni * 16 + (lane & 15);
            const int hd = n & 1023;
            const int h = hd >> 6, d = hd & 63;
            const float bias = (which == 0) ? f0[hd] : ((which == 2) ? f1[hd] : 0.f);
#pragma unroll
            for (int mi = 0; mi < 8; ++mi) {
#pragma unroll
                for (int j = 0; j < 4; ++j) {
                    const int m = m0 + wr * 128 + mi * 16 + ((lane >> 4) << 2) + j;
                    if (m >= MV) continue;
                    const int b = m / SEQ;
                    const int s = m - b * SEQ;
                    const int bh = b * 16 + h;
                    const float v = acc[mi][ni][j];
                    if (which == 0)      o0[((size_t)bh * SEQP + s) * 64 + d] = f2bf((v + bias) * 0.125f);
                    else if (which == 1) o1[((size_t)bh * SEQP + s) * 64 + d] = f2bf(v);
                    else                 o2[((size_t)bh * 64 + d) * VCOLS + s] = f2bf(v + bias);
                }
            }
        }
    } else {
#pragma unroll
        for (int ni = 0; ni < 4; ++ni) {
            const int n = n0 + wc * 64 + ni * 16 + (lane & 15);
            const float pb = f0[n];
#pragma unroll
            for (int mi = 0; mi < 8; ++mi) {
#pragma unroll
                for (int j = 0; j < 4; ++j) {
                    const int m = m0 + wr * 128 + mi * 16 + ((lane >> 4) << 2) + j;
                    if (m < MV) fout[(size_t)m * KDIM + n] = acc[mi][ni][j] + pb;
                }
            }
        }
    }
#undef TILE
#undef STAGE_A
#undef STAGE_B
#undef BAR
#undef WLG
#undef LDA4
#undef LDB4
#undef MFMA_PH
}

// ---------------------------------------------------------------------------
// attention: one block per (b,h). Unchanged from round 2 (passing).
// ---------------------------------------------------------------------------
__global__ __launch_bounds__(256) void attn_k(
    const unsigned short* __restrict__ qb, const unsigned short* __restrict__ kb,
    const unsigned short* __restrict__ vtb, const float* __restrict__ biasb,
    unsigned short* __restrict__ ao)
{
    __shared__ __attribute__((aligned(16))) unsigned short Ks[SEQP * 64];
    __shared__ __attribute__((aligned(16))) unsigned short Vs[64 * VCOLS];
    __shared__ __attribute__((aligned(16))) unsigned short Ps[4][640];

    const int bh = blockIdx.x;
    const int b = bh >> 4, h = bh & 15;
    const int tid = threadIdx.x;
    const int lane = tid & 63;
    const int wid = tid >> 6;

    {
        const unsigned short* kbase = kb + (size_t)bh * (SEQP * 64);
        const int swzel = (((lane & 7) ^ ((lane >> 3) & 7)) << 3);
        for (int c = wid; c < 34; c += 4)
            gll16((char*)Ks + c * 1024, kbase + (c * 8 + (lane >> 3)) * 64 + swzel);
        const char* vbase = (const char*)(vtb + (size_t)bh * (64 * VCOLS));
        for (int c = wid; c < 40; c += 4) {
            const int o = c * 1024 + lane * 16;
            const int r = o / 640;
            const int cbv = o - r * 640;
            const int csrc = cbv ^ ((r & 7) << 4);
            gll16((char*)Vs + c * 1024, vbase + r * 640 + csrc);
        }
    }
    asm volatile("s_waitcnt vmcnt(0)" ::: "memory");
    __syncthreads();

    const unsigned short* qbase = qb + (size_t)bh * (SEQP * 64);
    const float* bbase = biasb + (size_t)h * (SEQP * SEQP);

#pragma unroll 1
    for (int qt = wid; qt < 17; qt += 4) {
        const int qr0 = qt * 16;
        const bf16x8 aq0 = *(const bf16x8*)(qbase + (qr0 + (lane & 15)) * 64 + ((lane >> 4) << 3));
        const bf16x8 aq1 = *(const bf16x8*)(qbase + (qr0 + (lane & 15)) * 64 + 32 + ((lane >> 4) << 3));

        f32x4 s[17];
        const int cb0 = (((lane >> 4) << 4)) ^ ((lane & 7) << 4);
        const int cb1 = (64 + ((lane >> 4) << 4)) ^ ((lane & 7) << 4);
#pragma unroll
        for (int nt = 0; nt < 17; ++nt) {
            const int Rb = (nt * 16 + (lane & 15)) * 128;
            const bf16x8 bk0 = *(const bf16x8*)((const char*)Ks + Rb + cb0);
            const bf16x8 bk1 = *(const bf16x8*)((const char*)Ks + Rb + cb1);
            f32x4 z = 0.f;
            z = MFMA16(aq0, bk0, z);
            s[nt] = MFMA16(aq1, bk1, z);
        }

        float mx[4] = {-1e30f, -1e30f, -1e30f, -1e30f};
#pragma unroll
        for (int nt = 0; nt < 17; ++nt) {
            const int kcol = nt * 16 + (lane & 15);
            const bool ok = (nt < 16) || ((lane & 15) == 0);  // kcol < 257
#pragma unroll
            for (int j = 0; j < 4; ++j) {
                const int qr = qr0 + ((lane >> 4) << 2) + j;
                const float t = ok ? (s[nt][j] + bbase[qr * SEQP + kcol]) : -1e30f;
                s[nt][j] = t;
                mx[j] = fmaxf(mx[j], t);
            }
        }
#pragma unroll
        for (int j = 0; j < 4; ++j) {
            mx[j] = fmaxf(mx[j], __shfl_xor(mx[j], 1));
            mx[j] = fmaxf(mx[j], __shfl_xor(mx[j], 2));
            mx[j] = fmaxf(mx[j], __shfl_xor(mx[j], 4));
            mx[j] = fmaxf(mx[j], __shfl_xor(mx[j], 8));
        }
        float sm[4] = {0.f, 0.f, 0.f, 0.f};
#pragma unroll
        for (int nt = 0; nt < 17; ++nt)
#pragma unroll
            for (int j = 0; j < 4; ++j) {
                const float p = __expf(s[nt][j] - mx[j]);
                s[nt][j] = p;
                sm[j] += p;
            }
#pragma unroll
        for (int j = 0; j < 4; ++j) {
            sm[j] += __shfl_xor(sm[j], 1);
            sm[j] += __shfl_xor(sm[j], 2);
            sm[j] += __shfl_xor(sm[j], 4);
            sm[j] += __shfl_xor(sm[j], 8);
        }

        f32x4 o[4];
#pragma unroll
        for (int dt = 0; dt < 4; ++dt) o[dt] = 0.f;
        unsigned short* myP = &Ps[wid][0];
#pragma unroll
        for (int c = 0; c < 9; ++c) {
#pragma unroll
            for (int j = 0; j < 4; ++j) {
                const int row = ((lane >> 4) << 2) + j;
                myP[row * 40 + (lane & 15)] = f2bf(s[2 * c][j]);
                unsigned short hv = 0;
                if (c < 8) hv = f2bf(s[2 * c + 1][j]);
                myP[row * 40 + 16 + (lane & 15)] = hv;
            }
            asm volatile("s_waitcnt lgkmcnt(0)" ::: "memory");
            __builtin_amdgcn_sched_barrier(0);
            const bf16x8 pa = *(const bf16x8*)(myP + (lane & 15) * 40 + ((lane >> 4) << 3));
#pragma unroll
            for (int dt = 0; dt < 4; ++dt) {
                const int R = dt * 16 + (lane & 15);
                const int cbv = (c * 64 + ((lane >> 4) << 4)) ^ ((lane & 7) << 4);
                const bf16x8 bv = *(const bf16x8*)((const char*)Vs + R * 640 + cbv);
                o[dt] = MFMA16(pa, bv, o[dt]);
            }
        }

#pragma unroll
        for (int j = 0; j < 4; ++j) {
            const int qr = qr0 + ((lane >> 4) << 2) + j;
            if (qr < SEQ) {
                const float inv = 1.0f / sm[j];
                const size_t rowoff = ((size_t)(b * SEQ + qr)) * KDIM + h * 64;
#pragma unroll
                for (int dt = 0; dt < 4; ++dt)
                    ao[rowoff + dt * 16 + (lane & 15)] = f2bf(o[dt][j] * inv);
            }
        }
    }
}

// ---------------------------------------------------------------------------
extern "C" void kernel_launch(void* const* d_in, const int* in_sizes, int n_in,
                              void* d_out, int out_size, void* d_ws, size_t ws_size,
                              hipStream_t stream) {
    const float* x       = (const float*)d_in[0];
    const float* qkv_w   = (const float*)d_in[1];
    const float* q_bias  = (const float*)d_in[2];
    const float* v_bias  = (const float*)d_in[3];
    const float* table   = (const float*)d_in[4];
    const float* proj_w  = (const float*)d_in[5];
    const float* proj_b  = (const float*)d_in[6];
    const int*   rpi     = (const int*)d_in[7];
    float* out = (float*)d_out;

    // workspace layout (~153 MB); xb is reused as ao after the QKV GEMM
    char* w = (char*)d_ws;
    unsigned short* xb  = (unsigned short*)(w);                 // [16512][1024] bf16 (also ao)
    unsigned short* wqb = (unsigned short*)(w + 33816576);      // [3072][1024]
    unsigned short* wpb = (unsigned short*)(w + 40108032);      // [1024][1024]
    float*          bb  = (float*)(w + 42205184);               // [16][272][272]
    unsigned short* qbf = (unsigned short*)(w + 46940160);      // [1024][272][64]
    unsigned short* kbf = (unsigned short*)(w + 82591744);      // [1024][272][64]
    unsigned short* vtb = (unsigned short*)(w + 118243328);     // [1024][64][320]

    convert_k<<<2048, 256, 0, stream>>>(x, qkv_w, proj_w, xb, wqb, wpb);
    bias_k<<<512, 256, 0, stream>>>(table, rpi, bb);
    // QKV: M-tiles 65 (16640 padded, staged reads clamped), N-tiles 12
    gemm8<12, 0><<<65 * 12, 512, 0, stream>>>(
        xb, wqb, q_bias, v_bias, qbf, kbf, vtb, nullptr);
    attn_k<<<1024, 256, 0, stream>>>(qbf, kbf, vtb, bb, xb);
    // proj: N-tiles 4
    gemm8<4, 1><<<65 * 4, 512, 0, stream>>>(
        xb, wpb, proj_b, nullptr, nullptr, nullptr, nullptr, out);
}

// Round 4
// 365.641 us; speedup vs baseline: 1.0769x; 1.0769x over previous
//
#include <hip/hip_runtime.h>

// ---------------------------------------------------------------------------
// BEiT-style attention block on MI355X (gfx950), bf16-MFMA pipeline.
// B=64, N=257 (pad 272), DIM=1024, HEADS=16, d=64.
// Round 4: revert to the proven 128x128 GEMM structure (r2), upgrade its
// K-loop to the catalog's "minimum 2-phase": double-buffered LDS,
// STAGE(next) issued BEFORE compute(current), single vmcnt(0)+s_barrier
// per K-step (r2 exposed full staging latency between two barriers).
// ---------------------------------------------------------------------------

typedef __attribute__((ext_vector_type(8))) short bf16x8;
typedef __attribute__((ext_vector_type(4))) float f32x4;

#define MFMA16(A, B, C) __builtin_amdgcn_mfma_f32_16x16x32_bf16((A), (B), (C), 0, 0, 0)

#define MV   16448   // valid rows = B*N
#define KDIM 1024
#define SEQ  257
#define SEQP 272
#define VCOLS 320

__device__ __forceinline__ void gll16(void* lds, const void* g) {
    // async global->LDS, 16B per lane; LDS dest is wave-uniform base + lane*16
    __builtin_amdgcn_global_load_lds(
        (const __attribute__((address_space(1))) void*)g,
        (__attribute__((address_space(3))) void*)lds,
        16, 0, 0);
}

__device__ __forceinline__ unsigned short f2bf(float f) {
    union { float f; unsigned int u; } x;
    x.f = f;
    unsigned int r = x.u + 0x7FFFu + ((x.u >> 16) & 1u);  // RNE
    return (unsigned short)(r >> 16);
}

// ---------------------------------------------------------------------------
__global__ __launch_bounds__(256) void convert_k(
    const float* __restrict__ x, const float* __restrict__ wq, const float* __restrict__ wp,
    unsigned short* __restrict__ xb, unsigned short* __restrict__ wqb, unsigned short* __restrict__ wpb)
{
    const int XT = MV * KDIM / 4;
    const int QT = 3072 * KDIM / 4;
    const int PT = KDIM * KDIM / 4;
    const int total = XT + QT + PT;
    for (int i = blockIdx.x * blockDim.x + threadIdx.x; i < total; i += gridDim.x * blockDim.x) {
        const float4* s; unsigned short* d; int g;
        if (i < XT)            { s = (const float4*)x;  d = xb;  g = i; }
        else if (i < XT + QT)  { s = (const float4*)wq; d = wqb; g = i - XT; }
        else                   { s = (const float4*)wp; d = wpb; g = i - XT - QT; }
        float4 v = s[g];
        ushort4 u;
        u.x = f2bf(v.x); u.y = f2bf(v.y); u.z = f2bf(v.z); u.w = f2bf(v.w);
        *(ushort4*)(d + (size_t)g * 4) = u;
    }
}

// ---------------------------------------------------------------------------
__global__ __launch_bounds__(256) void bias_k(
    const float* __restrict__ table, const int* __restrict__ rpi, float* __restrict__ biasb)
{
    const int total = 16 * SEQP * SEQP;
    for (int i = blockIdx.x * blockDim.x + threadIdx.x; i < total; i += gridDim.x * blockDim.x) {
        int h = i / (SEQP * SEQP);
        int rem = i - h * (SEQP * SEQP);
        int q = rem / SEQP;
        int k = rem - q * SEQP;
        float v = 0.f;
        if (q < SEQ && k < SEQ) v = table[rpi[q * SEQ + k] * 16 + h];
        biasb[i] = v;
    }
}

// ---------------------------------------------------------------------------
// GEMM  C[m][n] = sum_k A[m][k] * W[n][k]  (row-major bf16, K=1024).
// 128x128 tile, 4 waves (2x2), 16x16x32 MFMA, XOR-swizzled dbuf LDS (64KB),
// minimum-2-phase K-loop: STAGE(next)->compute(cur)->vmcnt(0)->barrier.
// EPI==0: qkv epilogue (scatter q/k/v^T + bias + q-scale), EPI==1: proj.
// ---------------------------------------------------------------------------
template <int EPI>
__global__ __launch_bounds__(256) void gemm_bt(
    const unsigned short* __restrict__ A,
    const unsigned short* __restrict__ W,
    const float* __restrict__ f0,      // q_bias | proj_b
    const float* __restrict__ f1,      // v_bias | unused
    unsigned short* __restrict__ o0,   // q [bh][272][64]
    unsigned short* __restrict__ o1,   // k [bh][272][64]
    unsigned short* __restrict__ o2,   // v^T [bh][64][320]
    float* __restrict__ fout)          // proj out [MV][1024]
{
    __shared__ __attribute__((aligned(16))) unsigned short As[2][128 * 64];  // 2x16KB
    __shared__ __attribute__((aligned(16))) unsigned short Bs[2][128 * 64];  // 2x16KB
    const int tid = threadIdx.x;
    const int lane = tid & 63;
    const int wid = tid >> 6;
    const int wr = wid >> 1, wc = wid & 1;
    const int m0 = blockIdx.y * 128;
    const int n0 = blockIdx.x * 128;

    // staging: LDS linear offset o = wid*4096 + it*1024 + lane*16 (bytes)
    // row r = o>>7 (128B rows), src col-byte = (o&127) ^ ((r&7)<<4)
    const int swzel = (((lane & 7) ^ ((lane >> 3) & 7)) << 3);  // elements
    const size_t arow = (size_t)(m0 + wid * 32 + (lane >> 3)) * KDIM + swzel;
    const size_t wrow = (size_t)(n0 + wid * 32 + (lane >> 3)) * KDIM + swzel;

#define STAGE(P, KT) do { _Pragma("unroll") for (int it = 0; it < 4; ++it) { \
    gll16((char*)As[P] + wid * 4096 + it * 1024, A + arow + (size_t)it * 8 * KDIM + (KT) * 64); \
    gll16((char*)Bs[P] + wid * 4096 + it * 1024, W + wrow + (size_t)it * 8 * KDIM + (KT) * 64); } } while (0)

#define STEP(P, KT) do { \
    if ((KT) < 15) STAGE(1 - (P), (KT) + 1); \
    bf16x8 av[2][4], bv[2][4]; \
    _Pragma("unroll") for (int kk = 0; kk < 2; ++kk) { \
        const int cbs = (kk * 64 + ((lane >> 4) << 4)) ^ ((lane & 7) << 4); \
        _Pragma("unroll") for (int mi = 0; mi < 4; ++mi) { \
            const int R = wr * 64 + mi * 16 + (lane & 15); \
            av[kk][mi] = *(const bf16x8*)((const char*)As[P] + R * 128 + cbs); } \
        _Pragma("unroll") for (int ni = 0; ni < 4; ++ni) { \
            const int R = wc * 64 + ni * 16 + (lane & 15); \
            bv[kk][ni] = *(const bf16x8*)((const char*)Bs[P] + R * 128 + cbs); } } \
    asm volatile("s_waitcnt lgkmcnt(0)" ::: "memory"); \
    __builtin_amdgcn_sched_barrier(0); \
    _Pragma("unroll") for (int kk = 0; kk < 2; ++kk) \
        _Pragma("unroll") for (int mi = 0; mi < 4; ++mi) \
            _Pragma("unroll") for (int ni = 0; ni < 4; ++ni) \
                acc[mi][ni] = MFMA16(av[kk][mi], bv[kk][ni], acc[mi][ni]); \
    if ((KT) < 15) { asm volatile("s_waitcnt vmcnt(0)" ::: "memory"); } \
    asm volatile("" ::: "memory"); \
    __builtin_amdgcn_s_barrier(); \
    asm volatile("" ::: "memory"); \
} while (0)

    f32x4 acc[4][4];
#pragma unroll
    for (int i = 0; i < 4; ++i)
#pragma unroll
        for (int j = 0; j < 4; ++j) acc[i][j] = 0.f;

    // prologue: stage tile 0
    STAGE(0, 0);
    asm volatile("s_waitcnt vmcnt(0)" ::: "memory");
    asm volatile("" ::: "memory");
    __builtin_amdgcn_s_barrier();
    asm volatile("" ::: "memory");

#pragma unroll 1
    for (int ku = 0; ku < 8; ++ku) {
        const int kt0 = ku * 2;
        STEP(0, kt0);
        STEP(1, kt0 + 1);
    }
#undef STEP
#undef STAGE

    // C/D layout: col = lane&15, row = (lane>>4)*4 + j
    if (EPI == 0) {
        const int which = n0 >> 10;  // uniform per block: 0=q 1=k 2=v
#pragma unroll
        for (int ni = 0; ni < 4; ++ni) {
            const int n = n0 + wc * 64 + ni * 16 + (lane & 15);
            const int hd = n & 1023;
            const int h = hd >> 6, d = hd & 63;
            const float bias = (which == 0) ? f0[hd] : ((which == 2) ? f1[hd] : 0.f);
#pragma unroll
            for (int mi = 0; mi < 4; ++mi) {
#pragma unroll
                for (int j = 0; j < 4; ++j) {
                    const int m = m0 + wr * 64 + mi * 16 + ((lane >> 4) << 2) + j;
                    if (m >= MV) continue;
                    const int b = m / SEQ;
                    const int s = m - b * SEQ;
                    const int bh = b * 16 + h;
                    const float v = acc[mi][ni][j];
                    if (which == 0)      o0[((size_t)bh * SEQP + s) * 64 + d] = f2bf((v + bias) * 0.125f);
                    else if (which == 1) o1[((size_t)bh * SEQP + s) * 64 + d] = f2bf(v);
                    else                 o2[((size_t)bh * 64 + d) * VCOLS + s] = f2bf(v + bias);
                }
            }
        }
    } else {
#pragma unroll
        for (int ni = 0; ni < 4; ++ni) {
            const int n = n0 + wc * 64 + ni * 16 + (lane & 15);
            const float pb = f0[n];
#pragma unroll
            for (int mi = 0; mi < 4; ++mi) {
#pragma unroll
                for (int j = 0; j < 4; ++j) {
                    const int m = m0 + wr * 64 + mi * 16 + ((lane >> 4) << 2) + j;
                    if (m < MV) fout[(size_t)m * KDIM + n] = acc[mi][ni][j] + pb;
                }
            }
        }
    }
}

// ---------------------------------------------------------------------------
// attention: one block per (b,h). Unchanged from round 2 (passing).
// ---------------------------------------------------------------------------
__global__ __launch_bounds__(256) void attn_k(
    const unsigned short* __restrict__ qb, const unsigned short* __restrict__ kb,
    const unsigned short* __restrict__ vtb, const float* __restrict__ biasb,
    unsigned short* __restrict__ ao)
{
    __shared__ __attribute__((aligned(16))) unsigned short Ks[SEQP * 64];
    __shared__ __attribute__((aligned(16))) unsigned short Vs[64 * VCOLS];
    __shared__ __attribute__((aligned(16))) unsigned short Ps[4][640];

    const int bh = blockIdx.x;
    const int b = bh >> 4, h = bh & 15;
    const int tid = threadIdx.x;
    const int lane = tid & 63;
    const int wid = tid >> 6;

    {
        const unsigned short* kbase = kb + (size_t)bh * (SEQP * 64);
        const int swzel = (((lane & 7) ^ ((lane >> 3) & 7)) << 3);
        for (int c = wid; c < 34; c += 4)
            gll16((char*)Ks + c * 1024, kbase + (c * 8 + (lane >> 3)) * 64 + swzel);
        const char* vbase = (const char*)(vtb + (size_t)bh * (64 * VCOLS));
        for (int c = wid; c < 40; c += 4) {
            const int o = c * 1024 + lane * 16;
            const int r = o / 640;
            const int cbv = o - r * 640;
            const int csrc = cbv ^ ((r & 7) << 4);
            gll16((char*)Vs + c * 1024, vbase + r * 640 + csrc);
        }
    }
    asm volatile("s_waitcnt vmcnt(0)" ::: "memory");
    __syncthreads();

    const unsigned short* qbase = qb + (size_t)bh * (SEQP * 64);
    const float* bbase = biasb + (size_t)h * (SEQP * SEQP);

#pragma unroll 1
    for (int qt = wid; qt < 17; qt += 4) {
        const int qr0 = qt * 16;
        const bf16x8 aq0 = *(const bf16x8*)(qbase + (qr0 + (lane & 15)) * 64 + ((lane >> 4) << 3));
        const bf16x8 aq1 = *(const bf16x8*)(qbase + (qr0 + (lane & 15)) * 64 + 32 + ((lane >> 4) << 3));

        f32x4 s[17];
        const int cb0 = (((lane >> 4) << 4)) ^ ((lane & 7) << 4);
        const int cb1 = (64 + ((lane >> 4) << 4)) ^ ((lane & 7) << 4);
#pragma unroll
        for (int nt = 0; nt < 17; ++nt) {
            const int Rb = (nt * 16 + (lane & 15)) * 128;
            const bf16x8 bk0 = *(const bf16x8*)((const char*)Ks + Rb + cb0);
            const bf16x8 bk1 = *(const bf16x8*)((const char*)Ks + Rb + cb1);
            f32x4 z = 0.f;
            z = MFMA16(aq0, bk0, z);
            s[nt] = MFMA16(aq1, bk1, z);
        }

        float mx[4] = {-1e30f, -1e30f, -1e30f, -1e30f};
#pragma unroll
        for (int nt = 0; nt < 17; ++nt) {
            const int kcol = nt * 16 + (lane & 15);
            const bool ok = (nt < 16) || ((lane & 15) == 0);  // kcol < 257
#pragma unroll
            for (int j = 0; j < 4; ++j) {
                const int qr = qr0 + ((lane >> 4) << 2) + j;
                const float t = ok ? (s[nt][j] + bbase[qr * SEQP + kcol]) : -1e30f;
                s[nt][j] = t;
                mx[j] = fmaxf(mx[j], t);
            }
        }
#pragma unroll
        for (int j = 0; j < 4; ++j) {
            mx[j] = fmaxf(mx[j], __shfl_xor(mx[j], 1));
            mx[j] = fmaxf(mx[j], __shfl_xor(mx[j], 2));
            mx[j] = fmaxf(mx[j], __shfl_xor(mx[j], 4));
            mx[j] = fmaxf(mx[j], __shfl_xor(mx[j], 8));
        }
        float sm[4] = {0.f, 0.f, 0.f, 0.f};
#pragma unroll
        for (int nt = 0; nt < 17; ++nt)
#pragma unroll
            for (int j = 0; j < 4; ++j) {
                const float p = __expf(s[nt][j] - mx[j]);
                s[nt][j] = p;
                sm[j] += p;
            }
#pragma unroll
        for (int j = 0; j < 4; ++j) {
            sm[j] += __shfl_xor(sm[j], 1);
            sm[j] += __shfl_xor(sm[j], 2);
            sm[j] += __shfl_xor(sm[j], 4);
            sm[j] += __shfl_xor(sm[j], 8);
        }

        f32x4 o[4];
#pragma unroll
        for (int dt = 0; dt < 4; ++dt) o[dt] = 0.f;
        unsigned short* myP = &Ps[wid][0];
#pragma unroll
        for (int c = 0; c < 9; ++c) {
#pragma unroll
            for (int j = 0; j < 4; ++j) {
                const int row = ((lane >> 4) << 2) + j;
                myP[row * 40 + (lane & 15)] = f2bf(s[2 * c][j]);
                unsigned short hv = 0;
                if (c < 8) hv = f2bf(s[2 * c + 1][j]);
                myP[row * 40 + 16 + (lane & 15)] = hv;
            }
            asm volatile("s_waitcnt lgkmcnt(0)" ::: "memory");
            __builtin_amdgcn_sched_barrier(0);
            const bf16x8 pa = *(const bf16x8*)(myP + (lane & 15) * 40 + ((lane >> 4) << 3));
#pragma unroll
            for (int dt = 0; dt < 4; ++dt) {
                const int R = dt * 16 + (lane & 15);
                const int cbv = (c * 64 + ((lane >> 4) << 4)) ^ ((lane & 7) << 4);
                const bf16x8 bv = *(const bf16x8*)((const char*)Vs + R * 640 + cbv);
                o[dt] = MFMA16(pa, bv, o[dt]);
            }
        }

#pragma unroll
        for (int j = 0; j < 4; ++j) {
            const int qr = qr0 + ((lane >> 4) << 2) + j;
            if (qr < SEQ) {
                const float inv = 1.0f / sm[j];
                const size_t rowoff = ((size_t)(b * SEQ + qr)) * KDIM + h * 64;
#pragma unroll
                for (int dt = 0; dt < 4; ++dt)
                    ao[rowoff + dt * 16 + (lane & 15)] = f2bf(o[dt][j] * inv);
            }
        }
    }
}

// ---------------------------------------------------------------------------
extern "C" void kernel_launch(void* const* d_in, const int* in_sizes, int n_in,
                              void* d_out, int out_size, void* d_ws, size_t ws_size,
                              hipStream_t stream) {
    const float* x       = (const float*)d_in[0];
    const float* qkv_w   = (const float*)d_in[1];
    const float* q_bias  = (const float*)d_in[2];
    const float* v_bias  = (const float*)d_in[3];
    const float* table   = (const float*)d_in[4];
    const float* proj_w  = (const float*)d_in[5];
    const float* proj_b  = (const float*)d_in[6];
    const int*   rpi     = (const int*)d_in[7];
    float* out = (float*)d_out;

    // workspace layout (~153 MB); xb is reused as ao after the QKV GEMM
    char* w = (char*)d_ws;
    unsigned short* xb  = (unsigned short*)(w);                 // [16512][1024] bf16 (also ao)
    unsigned short* wqb = (unsigned short*)(w + 33816576);      // [3072][1024]
    unsigned short* wpb = (unsigned short*)(w + 40108032);      // [1024][1024]
    float*          bb  = (float*)(w + 42205184);               // [16][272][272]
    unsigned short* qbf = (unsigned short*)(w + 46940160);      // [1024][272][64]
    unsigned short* kbf = (unsigned short*)(w + 82591744);      // [1024][272][64]
    unsigned short* vtb = (unsigned short*)(w + 118243328);     // [1024][64][320]

    convert_k<<<2048, 256, 0, stream>>>(x, qkv_w, proj_w, xb, wqb, wpb);
    bias_k<<<512, 256, 0, stream>>>(table, rpi, bb);
    gemm_bt<0><<<dim3(3072 / 128, 16512 / 128), 256, 0, stream>>>(
        xb, wqb, q_bias, v_bias, qbf, kbf, vtb, nullptr);
    attn_k<<<1024, 256, 0, stream>>>(qbf, kbf, vtb, bb, xb);
    gemm_bt<1><<<dim3(KDIM / 128, 16512 / 128), 256, 0, stream>>>(
        xb, wpb, proj_b, nullptr, nullptr, nullptr, nullptr, out);
}

// Round 5
// 347.475 us; speedup vs baseline: 1.1332x; 1.0523x over previous
//
#include <hip/hip_runtime.h>

// ---------------------------------------------------------------------------
// BEiT-style attention block on MI355X (gfx950), bf16-MFMA pipeline.
// B=64, N=257 (pad 272), DIM=1024, HEADS=16, d=64.
// Round 5: r2's K-loop restored (single-buffer, 2-barrier; 5 blocks/CU TLP
// beats explicit pipelining here — r3/r4 both regressed). New:
//  (a) v^T epilogue bounces through LDS -> coalesced row stores (was a
//      2B x 640B-stride scatter, ~16-64 sectors per wave-store);
//  (b) XCD-chunked flat-grid remap (T1): m-tile-major chunks keep each
//      XCD's A-panel L2-resident -> staging drains hit L2 not HBM.
// ---------------------------------------------------------------------------

typedef __attribute__((ext_vector_type(8))) short bf16x8;
typedef __attribute__((ext_vector_type(4))) float f32x4;

#define MFMA16(A, B, C) __builtin_amdgcn_mfma_f32_16x16x32_bf16((A), (B), (C), 0, 0, 0)

#define MV   16448   // valid rows = B*N
#define KDIM 1024
#define SEQ  257
#define SEQP 272
#define VCOLS 320

__device__ __forceinline__ void gll16(void* lds, const void* g) {
    // async global->LDS, 16B per lane; LDS dest is wave-uniform base + lane*16
    __builtin_amdgcn_global_load_lds(
        (const __attribute__((address_space(1))) void*)g,
        (__attribute__((address_space(3))) void*)lds,
        16, 0, 0);
}

__device__ __forceinline__ unsigned short f2bf(float f) {
    union { float f; unsigned int u; } x;
    x.f = f;
    unsigned int r = x.u + 0x7FFFu + ((x.u >> 16) & 1u);  // RNE
    return (unsigned short)(r >> 16);
}

// ---------------------------------------------------------------------------
__global__ __launch_bounds__(256) void convert_k(
    const float* __restrict__ x, const float* __restrict__ wq, const float* __restrict__ wp,
    unsigned short* __restrict__ xb, unsigned short* __restrict__ wqb, unsigned short* __restrict__ wpb)
{
    const int XT = MV * KDIM / 4;
    const int QT = 3072 * KDIM / 4;
    const int PT = KDIM * KDIM / 4;
    const int total = XT + QT + PT;
    for (int i = blockIdx.x * blockDim.x + threadIdx.x; i < total; i += gridDim.x * blockDim.x) {
        const float4* s; unsigned short* d; int g;
        if (i < XT)            { s = (const float4*)x;  d = xb;  g = i; }
        else if (i < XT + QT)  { s = (const float4*)wq; d = wqb; g = i - XT; }
        else                   { s = (const float4*)wp; d = wpb; g = i - XT - QT; }
        float4 v = s[g];
        ushort4 u;
        u.x = f2bf(v.x); u.y = f2bf(v.y); u.z = f2bf(v.z); u.w = f2bf(v.w);
        *(ushort4*)(d + (size_t)g * 4) = u;
    }
}

// ---------------------------------------------------------------------------
__global__ __launch_bounds__(256) void bias_k(
    const float* __restrict__ table, const int* __restrict__ rpi, float* __restrict__ biasb)
{
    const int total = 16 * SEQP * SEQP;
    for (int i = blockIdx.x * blockDim.x + threadIdx.x; i < total; i += gridDim.x * blockDim.x) {
        int h = i / (SEQP * SEQP);
        int rem = i - h * (SEQP * SEQP);
        int q = rem / SEQP;
        int k = rem - q * SEQP;
        float v = 0.f;
        if (q < SEQ && k < SEQ) v = table[rpi[q * SEQ + k] * 16 + h];
        biasb[i] = v;
    }
}

// ---------------------------------------------------------------------------
// GEMM  C[m][n] = sum_k A[m][k] * W[n][k]  (row-major bf16, K=1024).
// 128x128 tile, 4 waves (2x2), 16x16x32 MFMA, XOR-swizzled LDS (32KB),
// r2 K-loop: sync; STAGE; vmcnt(0); sync; compute.  Flat 1-D grid with
// XCD-chunked remap (NTN = n-tiles per m-row).
// EPI==0: qkv epilogue (q/k direct + v via LDS bounce), EPI==1: proj.
// ---------------------------------------------------------------------------
template <int NTN, int EPI>
__global__ __launch_bounds__(256) void gemm_bt(
    const unsigned short* __restrict__ A,
    const unsigned short* __restrict__ W,
    const float* __restrict__ f0,      // q_bias | proj_b
    const float* __restrict__ f1,      // v_bias | unused
    unsigned short* __restrict__ o0,   // q [bh][272][64]
    unsigned short* __restrict__ o1,   // k [bh][272][64]
    unsigned short* __restrict__ o2,   // v^T [bh][64][320]
    float* __restrict__ fout)          // proj out [MV][1024]
{
    __shared__ __attribute__((aligned(16))) unsigned short sh[2][128 * 64];  // As | Bs (32KB)
    unsigned short* As = sh[0];
    unsigned short* Bs = sh[1];
    const int tid = threadIdx.x;
    const int lane = tid & 63;
    const int wid = tid >> 6;
    const int wr = wid >> 1, wc = wid & 1;

    // XCD-chunked remap: consecutive blocks within an XCD walk m-tile-major
    // (A-panel 256KB stays L2-resident per XCD; grid divisible by 8).
    const int flat = blockIdx.x;
    const int chunk = gridDim.x >> 3;
    const int remap = (flat & 7) * chunk + (flat >> 3);
    const int mt = remap / NTN;
    const int m0 = mt * 128;
    const int n0 = (remap - mt * NTN) * 128;

    // staging: LDS linear offset o = wid*4096 + it*1024 + lane*16 (bytes)
    // row r = o>>7 (128B rows), src col-byte = (o&127) ^ ((r&7)<<4)
    const int swzel = (((lane & 7) ^ ((lane >> 3) & 7)) << 3);  // elements
    const size_t arow = (size_t)(m0 + wid * 32 + (lane >> 3)) * KDIM + swzel;
    const size_t wrow = (size_t)(n0 + wid * 32 + (lane >> 3)) * KDIM + swzel;

    f32x4 acc[4][4];
#pragma unroll
    for (int i = 0; i < 4; ++i)
#pragma unroll
        for (int j = 0; j < 4; ++j) acc[i][j] = 0.f;

    for (int kt = 0; kt < KDIM / 64; ++kt) {
        __syncthreads();
        const int kofs = kt * 64;
#pragma unroll
        for (int it = 0; it < 4; ++it) {
            gll16((char*)As + wid * 4096 + it * 1024, A + arow + (size_t)it * 8 * KDIM + kofs);
            gll16((char*)Bs + wid * 4096 + it * 1024, W + wrow + (size_t)it * 8 * KDIM + kofs);
        }
        asm volatile("s_waitcnt vmcnt(0)" ::: "memory");
        __syncthreads();
#pragma unroll
        for (int kk = 0; kk < 2; ++kk) {
            const int cbs = (kk * 64 + ((lane >> 4) << 4)) ^ ((lane & 7) << 4);
            bf16x8 av[4], bv[4];
#pragma unroll
            for (int mi = 0; mi < 4; ++mi) {
                const int R = wr * 64 + mi * 16 + (lane & 15);
                av[mi] = *(const bf16x8*)((const char*)As + R * 128 + cbs);
            }
#pragma unroll
            for (int ni = 0; ni < 4; ++ni) {
                const int R = wc * 64 + ni * 16 + (lane & 15);
                bv[ni] = *(const bf16x8*)((const char*)Bs + R * 128 + cbs);
            }
#pragma unroll
            for (int mi = 0; mi < 4; ++mi)
#pragma unroll
                for (int ni = 0; ni < 4; ++ni)
                    acc[mi][ni] = MFMA16(av[mi], bv[ni], acc[mi][ni]);
        }
    }

    // C/D layout: col = lane&15, row = (lane>>4)*4 + j
    if (EPI == 0) {
        const int which = n0 >> 10;  // uniform per block: 0=q 1=k 2=v
        if (which == 2) {
            // ---- v: bounce acc through LDS (K-loop done; last step's
            // lgkmcnt(0)+barrier retired all As/Bs reads) ----
            unsigned short* L = &sh[0][0];  // 32KB: [n_local][m_local] swizzled
#pragma unroll
            for (int ni = 0; ni < 4; ++ni) {
                const int n_local = wc * 64 + ni * 16 + (lane & 15);
                const int hd = (n0 + n_local) & 1023;
                const float bias = f1[hd];
#pragma unroll
                for (int mi = 0; mi < 4; ++mi) {
#pragma unroll
                    for (int j = 0; j < 4; ++j) {
                        const int m_local = wr * 64 + mi * 16 + ((lane >> 4) << 2) + j;
                        *(unsigned short*)((char*)L + n_local * 256 +
                            ((m_local * 2) ^ ((n_local & 15) << 4))) =
                            f2bf(acc[mi][ni][j] + bias);
                    }
                }
            }
            __syncthreads();
            // coalesced row stores: wave walks m (s) within one v^T row
#pragma unroll 1
            for (int rr = 0; rr < 32; ++rr) {
                const int n_local = wid * 32 + rr;
                const int hd = (n0 + n_local) & 1023;
                const int h = hd >> 6, d = hd & 63;
#pragma unroll
                for (int half = 0; half < 2; ++half) {
                    const int m_local = half * 64 + lane;
                    const int m = m0 + m_local;
                    if (m < MV) {
                        const unsigned short val = *(const unsigned short*)((char*)L +
                            n_local * 256 + ((m_local * 2) ^ ((n_local & 15) << 4)));
                        const int b = m / SEQ;
                        const int s = m - b * SEQ;
                        o2[((size_t)(b * 16 + h) * 64 + d) * VCOLS + s] = val;
                    }
                }
            }
        } else {
            // ---- q/k: direct stores (d-contiguous over lanes, 4 sectors) ----
#pragma unroll
            for (int ni = 0; ni < 4; ++ni) {
                const int n = n0 + wc * 64 + ni * 16 + (lane & 15);
                const int hd = n & 1023;
                const int h = hd >> 6, d = hd & 63;
                const float bias = (which == 0) ? f0[hd] : 0.f;
#pragma unroll
                for (int mi = 0; mi < 4; ++mi) {
#pragma unroll
                    for (int j = 0; j < 4; ++j) {
                        const int m = m0 + wr * 64 + mi * 16 + ((lane >> 4) << 2) + j;
                        if (m >= MV) continue;
                        const int b = m / SEQ;
                        const int s = m - b * SEQ;
                        const int bh = b * 16 + h;
                        const float v = acc[mi][ni][j];
                        if (which == 0) o0[((size_t)bh * SEQP + s) * 64 + d] = f2bf((v + bias) * 0.125f);
                        else            o1[((size_t)bh * SEQP + s) * 64 + d] = f2bf(v);
                    }
                }
            }
        }
    } else {
#pragma unroll
        for (int ni = 0; ni < 4; ++ni) {
            const int n = n0 + wc * 64 + ni * 16 + (lane & 15);
            const float pb = f0[n];
#pragma unroll
            for (int mi = 0; mi < 4; ++mi) {
#pragma unroll
                for (int j = 0; j < 4; ++j) {
                    const int m = m0 + wr * 64 + mi * 16 + ((lane >> 4) << 2) + j;
                    if (m < MV) fout[(size_t)m * KDIM + n] = acc[mi][ni][j] + pb;
                }
            }
        }
    }
}

// ---------------------------------------------------------------------------
// attention: one block per (b,h). Unchanged from round 2 (passing).
// ---------------------------------------------------------------------------
__global__ __launch_bounds__(256) void attn_k(
    const unsigned short* __restrict__ qb, const unsigned short* __restrict__ kb,
    const unsigned short* __restrict__ vtb, const float* __restrict__ biasb,
    unsigned short* __restrict__ ao)
{
    __shared__ __attribute__((aligned(16))) unsigned short Ks[SEQP * 64];
    __shared__ __attribute__((aligned(16))) unsigned short Vs[64 * VCOLS];
    __shared__ __attribute__((aligned(16))) unsigned short Ps[4][640];

    const int bh = blockIdx.x;
    const int b = bh >> 4, h = bh & 15;
    const int tid = threadIdx.x;
    const int lane = tid & 63;
    const int wid = tid >> 6;

    {
        const unsigned short* kbase = kb + (size_t)bh * (SEQP * 64);
        const int swzel = (((lane & 7) ^ ((lane >> 3) & 7)) << 3);
        for (int c = wid; c < 34; c += 4)
            gll16((char*)Ks + c * 1024, kbase + (c * 8 + (lane >> 3)) * 64 + swzel);
        const char* vbase = (const char*)(vtb + (size_t)bh * (64 * VCOLS));
        for (int c = wid; c < 40; c += 4) {
            const int o = c * 1024 + lane * 16;
            const int r = o / 640;
            const int cbv = o - r * 640;
            const int csrc = cbv ^ ((r & 7) << 4);
            gll16((char*)Vs + c * 1024, vbase + r * 640 + csrc);
        }
    }
    asm volatile("s_waitcnt vmcnt(0)" ::: "memory");
    __syncthreads();

    const unsigned short* qbase = qb + (size_t)bh * (SEQP * 64);
    const float* bbase = biasb + (size_t)h * (SEQP * SEQP);

#pragma unroll 1
    for (int qt = wid; qt < 17; qt += 4) {
        const int qr0 = qt * 16;
        const bf16x8 aq0 = *(const bf16x8*)(qbase + (qr0 + (lane & 15)) * 64 + ((lane >> 4) << 3));
        const bf16x8 aq1 = *(const bf16x8*)(qbase + (qr0 + (lane & 15)) * 64 + 32 + ((lane >> 4) << 3));

        f32x4 s[17];
        const int cb0 = (((lane >> 4) << 4)) ^ ((lane & 7) << 4);
        const int cb1 = (64 + ((lane >> 4) << 4)) ^ ((lane & 7) << 4);
#pragma unroll
        for (int nt = 0; nt < 17; ++nt) {
            const int Rb = (nt * 16 + (lane & 15)) * 128;
            const bf16x8 bk0 = *(const bf16x8*)((const char*)Ks + Rb + cb0);
            const bf16x8 bk1 = *(const bf16x8*)((const char*)Ks + Rb + cb1);
            f32x4 z = 0.f;
            z = MFMA16(aq0, bk0, z);
            s[nt] = MFMA16(aq1, bk1, z);
        }

        float mx[4] = {-1e30f, -1e30f, -1e30f, -1e30f};
#pragma unroll
        for (int nt = 0; nt < 17; ++nt) {
            const int kcol = nt * 16 + (lane & 15);
            const bool ok = (nt < 16) || ((lane & 15) == 0);  // kcol < 257
#pragma unroll
            for (int j = 0; j < 4; ++j) {
                const int qr = qr0 + ((lane >> 4) << 2) + j;
                const float t = ok ? (s[nt][j] + bbase[qr * SEQP + kcol]) : -1e30f;
                s[nt][j] = t;
                mx[j] = fmaxf(mx[j], t);
            }
        }
#pragma unroll
        for (int j = 0; j < 4; ++j) {
            mx[j] = fmaxf(mx[j], __shfl_xor(mx[j], 1));
            mx[j] = fmaxf(mx[j], __shfl_xor(mx[j], 2));
            mx[j] = fmaxf(mx[j], __shfl_xor(mx[j], 4));
            mx[j] = fmaxf(mx[j], __shfl_xor(mx[j], 8));
        }
        float sm[4] = {0.f, 0.f, 0.f, 0.f};
#pragma unroll
        for (int nt = 0; nt < 17; ++nt)
#pragma unroll
            for (int j = 0; j < 4; ++j) {
                const float p = __expf(s[nt][j] - mx[j]);
                s[nt][j] = p;
                sm[j] += p;
            }
#pragma unroll
        for (int j = 0; j < 4; ++j) {
            sm[j] += __shfl_xor(sm[j], 1);
            sm[j] += __shfl_xor(sm[j], 2);
            sm[j] += __shfl_xor(sm[j], 4);
            sm[j] += __shfl_xor(sm[j], 8);
        }

        f32x4 o[4];
#pragma unroll
        for (int dt = 0; dt < 4; ++dt) o[dt] = 0.f;
        unsigned short* myP = &Ps[wid][0];
#pragma unroll
        for (int c = 0; c < 9; ++c) {
#pragma unroll
            for (int j = 0; j < 4; ++j) {
                const int row = ((lane >> 4) << 2) + j;
                myP[row * 40 + (lane & 15)] = f2bf(s[2 * c][j]);
                unsigned short hv = 0;
                if (c < 8) hv = f2bf(s[2 * c + 1][j]);
                myP[row * 40 + 16 + (lane & 15)] = hv;
            }
            asm volatile("s_waitcnt lgkmcnt(0)" ::: "memory");
            __builtin_amdgcn_sched_barrier(0);
            const bf16x8 pa = *(const bf16x8*)(myP + (lane & 15) * 40 + ((lane >> 4) << 3));
#pragma unroll
            for (int dt = 0; dt < 4; ++dt) {
                const int R = dt * 16 + (lane & 15);
                const int cbv = (c * 64 + ((lane >> 4) << 4)) ^ ((lane & 7) << 4);
                const bf16x8 bv = *(const bf16x8*)((const char*)Vs + R * 640 + cbv);
                o[dt] = MFMA16(pa, bv, o[dt]);
            }
        }

#pragma unroll
        for (int j = 0; j < 4; ++j) {
            const int qr = qr0 + ((lane >> 4) << 2) + j;
            if (qr < SEQ) {
                const float inv = 1.0f / sm[j];
                const size_t rowoff = ((size_t)(b * SEQ + qr)) * KDIM + h * 64;
#pragma unroll
                for (int dt = 0; dt < 4; ++dt)
                    ao[rowoff + dt * 16 + (lane & 15)] = f2bf(o[dt][j] * inv);
            }
        }
    }
}

// ---------------------------------------------------------------------------
extern "C" void kernel_launch(void* const* d_in, const int* in_sizes, int n_in,
                              void* d_out, int out_size, void* d_ws, size_t ws_size,
                              hipStream_t stream) {
    const float* x       = (const float*)d_in[0];
    const float* qkv_w   = (const float*)d_in[1];
    const float* q_bias  = (const float*)d_in[2];
    const float* v_bias  = (const float*)d_in[3];
    const float* table   = (const float*)d_in[4];
    const float* proj_w  = (const float*)d_in[5];
    const float* proj_b  = (const float*)d_in[6];
    const int*   rpi     = (const int*)d_in[7];
    float* out = (float*)d_out;

    // workspace layout (~153 MB); xb is reused as ao after the QKV GEMM
    char* w = (char*)d_ws;
    unsigned short* xb  = (unsigned short*)(w);                 // [16512][1024] bf16 (also ao)
    unsigned short* wqb = (unsigned short*)(w + 33816576);      // [3072][1024]
    unsigned short* wpb = (unsigned short*)(w + 40108032);      // [1024][1024]
    float*          bb  = (float*)(w + 42205184);               // [16][272][272]
    unsigned short* qbf = (unsigned short*)(w + 46940160);      // [1024][272][64]
    unsigned short* kbf = (unsigned short*)(w + 82591744);      // [1024][272][64]
    unsigned short* vtb = (unsigned short*)(w + 118243328);     // [1024][64][320]

    convert_k<<<2048, 256, 0, stream>>>(x, qkv_w, proj_w, xb, wqb, wpb);
    bias_k<<<512, 256, 0, stream>>>(table, rpi, bb);
    // QKV: 129 m-tiles x 24 n-tiles = 3096 blocks (flat, XCD-remapped)
    gemm_bt<24, 0><<<3096, 256, 0, stream>>>(
        xb, wqb, q_bias, v_bias, qbf, kbf, vtb, nullptr);
    attn_k<<<1024, 256, 0, stream>>>(qbf, kbf, vtb, bb, xb);
    // proj: 129 x 8 = 1032 blocks
    gemm_bt<8, 1><<<1032, 256, 0, stream>>>(
        xb, wpb, proj_b, nullptr, nullptr, nullptr, nullptr, out);
}